// Round 3
// baseline (734.677 us; speedup 1.0000x reference)
//
#include <hip/hip_runtime.h>
#include <stdint.h>

#define NUM_NODES 1000000
#define H_DIM 64
#define OUT_DIM 32
#define NUM_RELS 64
#define NUM_BASES 4
#define N_SRC0 400000
#define N_DST1 100000
#define N_DST2 20000
#define E1 600000
#define E2 300000
#define NDST_TOT (N_DST1 + N_DST2)
#define E_TOT (E1 + E2)

typedef __attribute__((ext_vector_type(8))) short bf16x8;
typedef __attribute__((ext_vector_type(4))) float floatx4;

__device__ __forceinline__ unsigned short f2bf(float f){
  union{float f; unsigned u;} v; v.f=f;
  unsigned u=v.u;
  unsigned r=(u + 0x7FFFu + ((u>>16)&1u))>>16;
  return (unsigned short)r;
}
__device__ __forceinline__ float bf2f(unsigned short h){
  union{unsigned u; float f;} v; v.u=((unsigned)h)<<16; return v.f;
}

// ---- init: zero deg[120000] + build B fragment tables ----
__global__ void k_init(const float* __restrict__ V1, const float* __restrict__ V2,
                       ushort* __restrict__ Btab1, ushort* __restrict__ Btab2,
                       int* __restrict__ deg){
  int t = blockIdx.x*blockDim.x + threadIdx.x;
  if (t < NDST_TOT) deg[t] = 0;
  if (t < 16384){
    int j = t & 7, lane = (t>>3)&63, kk = (t>>9)&7, nt = t>>12;     // nt<4
    int kdim = kk*32 + (lane>>4)*8 + j;
    int o = nt*16 + (lane&15);
    int k = kdim>>2, b = kdim&3;
    Btab1[t] = f2bf(V1[(b*64 + k)*64 + o]);
  } else if (t < 24576){
    int u = t - 16384;
    int j = u & 7, lane = (u>>3)&63, kk = (u>>9)&7, nt = u>>12;     // nt<2
    int kdim = kk*32 + (lane>>4)*8 + j;
    int o = nt*16 + (lane&15);
    int k = kdim>>2, b = kdim&3;
    Btab2[u] = f2bf(V2[(b*64 + k)*32 + o]);
  }
}

// ---- histogram over both graphs' dst (graph2 offset by N_DST1) ----
__global__ void k_hist(const int* __restrict__ dst1, const int* __restrict__ dst2,
                       int* __restrict__ deg){
  int t = blockIdx.x*blockDim.x + threadIdx.x;
  if (t < E1) atomicAdd(&deg[dst1[t]], 1);
  else if (t < E_TOT) atomicAdd(&deg[N_DST1 + dst2[t - E1]], 1);
}

// ---- fused single-block exclusive scan over deg[NDST_TOT] ----
// 1024 threads, each owns a contiguous chunk of 118 elements. Two passes
// over deg (~1 MB through one CU, ~6us) but saves 2 dispatches + drains.
__global__ __launch_bounds__(1024) void k_scan(const int* __restrict__ deg,
                                               int* __restrict__ offs,
                                               int* __restrict__ cursor, int n){
  __shared__ int lds[1024];
  int tid = threadIdx.x;
  const int chunk = (n + 1023) >> 10;        // 118
  int lo = tid*chunk; if (lo > n) lo = n;
  int hi = lo + chunk; if (hi > n) hi = n;
  int s = 0;
  for (int i = lo; i < hi; i++) s += deg[i];
  lds[tid] = s; __syncthreads();
  for (int off = 1; off < 1024; off <<= 1){
    int t = (tid >= off) ? lds[tid-off] : 0; __syncthreads();
    lds[tid] += t; __syncthreads();
  }
  int run = lds[tid] - s;                    // global exclusive prefix
  for (int i = lo; i < hi; i++){
    offs[i] = run; cursor[i] = run; run += deg[i];
  }
  if (lo < n && hi == n) offs[n] = run;      // exactly one thread
}

// ---- scatter both graphs into dst-sorted PACKED edge meta ----
// meta[p] = { src | (etype<<20), norm } : 8 B per edge (was 20 B across
// two arrays). Coefficients comp[et]*norm are reconstructed in the agg
// kernels from the 1 KB comp table (wave-uniform -> scalar loads).
__global__ void k_scatter(const int* __restrict__ input_nodes,
                          const int* __restrict__ src1, const int* __restrict__ dst1,
                          const int* __restrict__ ety1, const float* __restrict__ nrm1,
                          const int* __restrict__ src2, const int* __restrict__ dst2,
                          const int* __restrict__ ety2, const float* __restrict__ nrm2,
                          int* __restrict__ cursor, uint2* __restrict__ meta){
  int t = blockIdx.x*blockDim.x + threadIdx.x;
  int d, s, et; float nv;
  if (t < E1){
    d = dst1[t]; s = input_nodes[src1[t]]; et = ety1[t]; nv = nrm1[t];
  } else if (t < E_TOT){
    int e = t - E1;
    d = N_DST1 + dst2[e]; s = src2[e]; et = ety2[e]; nv = nrm2[e];
  } else return;
  int p = atomicAdd(&cursor[d], 1);
  uint2 m; m.x = (unsigned)s | ((unsigned)et << 20);
  m.y = __float_as_uint(nv);
  meta[p] = m;
}

// ---- fused aggregate + GEMM per layer ----
// Block = 1024 threads = 16 waves, 16 dst rows: ONE row per wave. Edge
// loop is 8-wide unrolled with OOB edges clamped to e0 and masked to 0.
// Meta is wave-uniform 8 B; coeff = comp[et]*norm computed in-register.

__global__ __launch_bounds__(1024) void k_agg_gemm1(
    const float* __restrict__ emb, const int* __restrict__ offs,
    const uint2* __restrict__ meta, const float4* __restrict__ comp4,
    const ushort* __restrict__ Btab, const float* __restrict__ bias,
    ushort* __restrict__ h_bf){
  __shared__ ushort zt[16][264];
  int lane = threadIdx.x & 63;
  int w = threadIdx.x >> 6;            // 0..15, one dst row per wave
  int mbase = blockIdx.x * 16;
  int d = mbase + w;
  int e0 = __builtin_amdgcn_readfirstlane(offs[d]);
  int e1 = __builtin_amdgcn_readfirstlane(offs[d+1]);
  float a0=0.f, a1=0.f, a2=0.f, a3=0.f;
  for (int e = e0; e < e1; e += 8){
    int idx[8]; float msk[8];
    #pragma unroll
    for (int k=0;k<8;k++){
      int t = e + k;
      idx[k] = (t < e1) ? t : e0;
      msk[k] = (t < e1) ? 1.f : 0.f;
    }
    int s[8]; float4 c[8];
    #pragma unroll
    for (int k=0;k<8;k++){
      uint2 m = meta[idx[k]];
      unsigned pk = __builtin_amdgcn_readfirstlane(m.x);
      float nv = __uint_as_float(__builtin_amdgcn_readfirstlane(m.y));
      s[k] = (int)(pk & 0xFFFFFu);
      float4 cp = comp4[pk >> 20];
      c[k].x = cp.x*nv; c[k].y = cp.y*nv; c[k].z = cp.z*nv; c[k].w = cp.w*nv;
    }
    float x[8];
    #pragma unroll
    for (int k=0;k<8;k++)
      x[k] = emb[(size_t)s[k]*64 + lane] * msk[k];
    #pragma unroll
    for (int k=0;k<8;k++){
      a0 = fmaf(c[k].x, x[k], a0);
      a1 = fmaf(c[k].y, x[k], a1);
      a2 = fmaf(c[k].z, x[k], a2);
      a3 = fmaf(c[k].w, x[k], a3);
    }
  }
  ushort4 o; o.x=f2bf(a0); o.y=f2bf(a1); o.z=f2bf(a2); o.w=f2bf(a3);
  *(ushort4*)&zt[w][lane*4] = o;
  __syncthreads();
  if (w < 4){
    int quad = lane>>4, l15 = lane&15;
    bf16x8 a[8];
    #pragma unroll
    for (int kk=0; kk<8; kk++)
      a[kk] = *(const bf16x8*)&zt[l15][kk*32 + quad*8];
    floatx4 acc = {0.f,0.f,0.f,0.f};
    #pragma unroll
    for (int kk=0; kk<8; kk++){
      bf16x8 b = *((const bf16x8*)(Btab + ((w*8 + kk)*64 + lane)*8));
      acc = __builtin_amdgcn_mfma_f32_16x16x32_bf16(a[kk], b, acc, 0, 0, 0);
    }
    int col = w*16 + l15;
    float bv = bias[col];
    #pragma unroll
    for (int r=0; r<4; r++){
      int row = mbase + quad*4 + r;
      float v = fmaxf(acc[r] + bv, 0.f);
      h_bf[(size_t)row*64 + col] = f2bf(v);
    }
  }
}

__global__ __launch_bounds__(1024) void k_agg_gemm2(
    const ushort* __restrict__ hin, const int* __restrict__ offs,
    const uint2* __restrict__ meta, const float4* __restrict__ comp4,
    const ushort* __restrict__ Btab, const float* __restrict__ bias,
    float* __restrict__ out){
  __shared__ ushort zt[16][264];
  int lane = threadIdx.x & 63;
  int w = threadIdx.x >> 6;            // 0..15, one dst row per wave
  int mbase = blockIdx.x * 16;
  int d = mbase + w;
  int e0 = __builtin_amdgcn_readfirstlane(offs[d]);
  int e1 = __builtin_amdgcn_readfirstlane(offs[d+1]);
  float a0=0.f, a1=0.f, a2=0.f, a3=0.f;
  for (int e = e0; e < e1; e += 8){
    int idx[8]; float msk[8];
    #pragma unroll
    for (int k=0;k<8;k++){
      int t = e + k;
      idx[k] = (t < e1) ? t : e0;
      msk[k] = (t < e1) ? 1.f : 0.f;
    }
    int s[8]; float4 c[8];
    #pragma unroll
    for (int k=0;k<8;k++){
      uint2 m = meta[idx[k]];
      unsigned pk = __builtin_amdgcn_readfirstlane(m.x);
      float nv = __uint_as_float(__builtin_amdgcn_readfirstlane(m.y));
      s[k] = (int)(pk & 0xFFFFFu);
      float4 cp = comp4[pk >> 20];
      c[k].x = cp.x*nv; c[k].y = cp.y*nv; c[k].z = cp.z*nv; c[k].w = cp.w*nv;
    }
    float x[8];
    #pragma unroll
    for (int k=0;k<8;k++)
      x[k] = bf2f(hin[(size_t)s[k]*64 + lane]) * msk[k];
    #pragma unroll
    for (int k=0;k<8;k++){
      a0 = fmaf(c[k].x, x[k], a0);
      a1 = fmaf(c[k].y, x[k], a1);
      a2 = fmaf(c[k].z, x[k], a2);
      a3 = fmaf(c[k].w, x[k], a3);
    }
  }
  ushort4 o; o.x=f2bf(a0); o.y=f2bf(a1); o.z=f2bf(a2); o.w=f2bf(a3);
  *(ushort4*)&zt[w][lane*4] = o;
  __syncthreads();
  if (w < 2){                           // N=32 -> 2 n-tiles
    int quad = lane>>4, l15 = lane&15;
    bf16x8 a[8];
    #pragma unroll
    for (int kk=0; kk<8; kk++)
      a[kk] = *(const bf16x8*)&zt[l15][kk*32 + quad*8];
    floatx4 acc = {0.f,0.f,0.f,0.f};
    #pragma unroll
    for (int kk=0; kk<8; kk++){
      bf16x8 b = *((const bf16x8*)(Btab + ((w*8 + kk)*64 + lane)*8));
      acc = __builtin_amdgcn_mfma_f32_16x16x32_bf16(a[kk], b, acc, 0, 0, 0);
    }
    int col = w*16 + l15;
    float bv = bias[col];
    #pragma unroll
    for (int r=0; r<4; r++){
      int row = mbase + quad*4 + r;
      out[(size_t)row*32 + col] = acc[r] + bv;
    }
  }
}

extern "C" void kernel_launch(void* const* d_in, const int* in_sizes, int n_in,
                              void* d_out, int out_size, void* d_ws, size_t ws_size,
                              hipStream_t stream){
  const int*   input_nodes = (const int*)  d_in[0];
  const int*   src1  = (const int*)  d_in[1];
  const int*   dst1  = (const int*)  d_in[2];
  const int*   ety1  = (const int*)  d_in[3];
  const float* norm1 = (const float*)d_in[4];
  const int*   src2  = (const int*)  d_in[5];
  const int*   dst2  = (const int*)  d_in[6];
  const int*   ety2  = (const int*)  d_in[7];
  const float* norm2 = (const float*)d_in[8];
  const float* emb   = (const float*)d_in[9];
  const float* V1    = (const float*)d_in[10];
  const float* comp1 = (const float*)d_in[11];
  const float* b1    = (const float*)d_in[12];
  const float* V2    = (const float*)d_in[13];
  const float* comp2 = (const float*)d_in[14];
  const float* b2    = (const float*)d_in[15];
  float* out = (float*)d_out;

  char* p = (char*)d_ws;
  auto alloc = [&](size_t bytes)->char*{
    char* r = p; p += (bytes + 255) & ~(size_t)255; return r;
  };
  ushort* h_bf  = (ushort*)alloc((size_t)N_DST1*64*2);     // 12.8 MB
  ushort* Btab1 = (ushort*)alloc(16384*2);
  ushort* Btab2 = (ushort*)alloc(8192*2);
  int* deg  = (int*)alloc((size_t)NDST_TOT*4);
  int* cur  = (int*)alloc((size_t)NDST_TOT*4);
  int* offs = (int*)alloc((size_t)(NDST_TOT+1)*4);
  uint2* meta = (uint2*)alloc((size_t)E_TOT*8);

  // 1. init (deg zero + B tables)
  k_init<<<(NDST_TOT + 255)/256, 256, 0, stream>>>(V1, V2, Btab1, Btab2, deg);
  // 2. histogram (both graphs batched)
  k_hist<<<(E_TOT + 255)/256, 256, 0, stream>>>(dst1, dst2, deg);
  // 3. fused single-block exclusive scan
  k_scan<<<1, 1024, 0, stream>>>(deg, offs, cur, NDST_TOT);
  // 4. scatter both graphs (packed 8 B meta; resolves input_nodes for L1)
  k_scatter<<<(E_TOT + 255)/256, 256, 0, stream>>>(input_nodes,
                                                   src1, dst1, ety1, norm1,
                                                   src2, dst2, ety2, norm2,
                                                   cur, meta);
  // 5. layer 1 fused agg(direct emb)+gemm (+relu)
  k_agg_gemm1<<<N_DST1/16, 1024, 0, stream>>>(emb, offs, meta,
                                              (const float4*)comp1, Btab1, b1, h_bf);
  // 6. layer 2 fused agg+gemm -> out
  k_agg_gemm2<<<N_DST2/16, 1024, 0, stream>>>(h_bf, offs + N_DST1, meta,
                                              (const float4*)comp2, Btab2, b2, out);

  (void)in_sizes; (void)n_in; (void)out_size; (void)ws_size;
}

// Round 4
// 477.098 us; speedup vs baseline: 1.5399x; 1.5399x over previous
//
#include <hip/hip_runtime.h>
#include <stdint.h>

#define NUM_NODES 1000000
#define H_DIM 64
#define OUT_DIM 32
#define NUM_RELS 64
#define NUM_BASES 4
#define N_SRC0 400000
#define N_DST1 100000
#define N_DST2 20000
#define E1 600000
#define E2 300000
#define NDST_TOT (N_DST1 + N_DST2)
#define E_TOT (E1 + E2)

typedef __attribute__((ext_vector_type(8))) short bf16x8;
typedef __attribute__((ext_vector_type(4))) float floatx4;

__device__ __forceinline__ unsigned short f2bf(float f){
  union{float f; unsigned u;} v; v.f=f;
  unsigned u=v.u;
  unsigned r=(u + 0x7FFFu + ((u>>16)&1u))>>16;
  return (unsigned short)r;
}
__device__ __forceinline__ float bf2f(unsigned short h){
  union{unsigned u; float f;} v; v.u=((unsigned)h)<<16; return v.f;
}

// ---- init: zero deg[120000] + build B fragment tables ----
__global__ void k_init(const float* __restrict__ V1, const float* __restrict__ V2,
                       ushort* __restrict__ Btab1, ushort* __restrict__ Btab2,
                       int* __restrict__ deg){
  int t = blockIdx.x*blockDim.x + threadIdx.x;
  if (t < NDST_TOT) deg[t] = 0;
  if (t < 16384){
    int j = t & 7, lane = (t>>3)&63, kk = (t>>9)&7, nt = t>>12;     // nt<4
    int kdim = kk*32 + (lane>>4)*8 + j;
    int o = nt*16 + (lane&15);
    int k = kdim>>2, b = kdim&3;
    Btab1[t] = f2bf(V1[(b*64 + k)*64 + o]);
  } else if (t < 24576){
    int u = t - 16384;
    int j = u & 7, lane = (u>>3)&63, kk = (u>>9)&7, nt = u>>12;     // nt<2
    int kdim = kk*32 + (lane>>4)*8 + j;
    int o = nt*16 + (lane&15);
    int k = kdim>>2, b = kdim&3;
    Btab2[u] = f2bf(V2[(b*64 + k)*32 + o]);
  }
}

// ---- histogram over both graphs' dst (graph2 offset by N_DST1) ----
__global__ void k_hist(const int* __restrict__ dst1, const int* __restrict__ dst2,
                       int* __restrict__ deg){
  int t = blockIdx.x*blockDim.x + threadIdx.x;
  if (t < E1) atomicAdd(&deg[dst1[t]], 1);
  else if (t < E_TOT) atomicAdd(&deg[N_DST1 + dst2[t - E1]], 1);
}

// ---- 3-kernel exclusive scan over deg[NDST_TOT] (parallel, ~8us) ----
__global__ void k_scan_sum(const int* __restrict__ deg, int* __restrict__ bsum, int n){
  __shared__ int lds[256];
  int tid = threadIdx.x;
  int base = blockIdx.x*1024 + tid*4;
  int s = 0;
  #pragma unroll
  for (int j=0;j<4;j++){ int i = base+j; if (i<n) s += deg[i]; }
  lds[tid] = s; __syncthreads();
  for (int off=128; off>0; off>>=1){ if (tid<off) lds[tid] += lds[tid+off]; __syncthreads(); }
  if (tid==0) bsum[blockIdx.x] = lds[0];
}

__global__ void k_scan_bsum(const int* __restrict__ bsum, int* __restrict__ boff, int nb){
  __shared__ int lds[256];
  int tid = threadIdx.x;
  int v = (tid<nb) ? bsum[tid] : 0;
  lds[tid] = v; __syncthreads();
  for (int off=1; off<256; off<<=1){
    int t = (tid>=off) ? lds[tid-off] : 0; __syncthreads();
    lds[tid] += t; __syncthreads();
  }
  if (tid<nb) boff[tid] = lds[tid] - v;   // exclusive
}

__global__ void k_scan_final(const int* __restrict__ deg, const int* __restrict__ boff,
                             int* __restrict__ offs, int* __restrict__ cursor, int n){
  __shared__ int lds[256];
  int tid = threadIdx.x;
  int base = blockIdx.x*1024 + tid*4;
  int a[4]; int s = 0;
  #pragma unroll
  for (int j=0;j<4;j++){ int i = base+j; a[j] = (i<n)?deg[i]:0; s += a[j]; }
  lds[tid] = s; __syncthreads();
  for (int off=1; off<256; off<<=1){
    int t = (tid>=off) ? lds[tid-off] : 0; __syncthreads();
    lds[tid] += t; __syncthreads();
  }
  int run = boff[blockIdx.x] + (lds[tid] - s);   // global exclusive prefix
  #pragma unroll
  for (int j=0;j<4;j++){
    int i = base+j;
    if (i<n){
      offs[i] = run; cursor[i] = run;
      run += a[j];
      if (i == n-1) offs[n] = run;
    }
  }
}

// ---- scatter both graphs into dst-sorted PACKED edge meta ----
// meta[p] = { src | (etype<<20), norm } : 8 B per edge. Coefficients
// comp[et]*norm are reconstructed in the agg kernels from the 1 KB comp
// table (wave-uniform -> scalar loads).
__global__ void k_scatter(const int* __restrict__ input_nodes,
                          const int* __restrict__ src1, const int* __restrict__ dst1,
                          const int* __restrict__ ety1, const float* __restrict__ nrm1,
                          const int* __restrict__ src2, const int* __restrict__ dst2,
                          const int* __restrict__ ety2, const float* __restrict__ nrm2,
                          int* __restrict__ cursor, uint2* __restrict__ meta){
  int t = blockIdx.x*blockDim.x + threadIdx.x;
  int d, s, et; float nv;
  if (t < E1){
    d = dst1[t]; s = input_nodes[src1[t]]; et = ety1[t]; nv = nrm1[t];
  } else if (t < E_TOT){
    int e = t - E1;
    d = N_DST1 + dst2[e]; s = src2[e]; et = ety2[e]; nv = nrm2[e];
  } else return;
  int p = atomicAdd(&cursor[d], 1);
  uint2 m; m.x = (unsigned)s | ((unsigned)et << 20);
  m.y = __float_as_uint(nv);
  meta[p] = m;
}

// ---- fused aggregate + GEMM per layer ----
// Block = 1024 threads = 16 waves, 16 dst rows: ONE row per wave. Edge
// loop is 8-wide unrolled with OOB edges clamped to e0 and masked to 0.
// Meta is wave-uniform 8 B; coeff = comp[et]*norm computed in-register.

__global__ __launch_bounds__(1024) void k_agg_gemm1(
    const float* __restrict__ emb, const int* __restrict__ offs,
    const uint2* __restrict__ meta, const float4* __restrict__ comp4,
    const ushort* __restrict__ Btab, const float* __restrict__ bias,
    ushort* __restrict__ h_bf){
  __shared__ ushort zt[16][264];
  int lane = threadIdx.x & 63;
  int w = threadIdx.x >> 6;            // 0..15, one dst row per wave
  int mbase = blockIdx.x * 16;
  int d = mbase + w;
  int e0 = __builtin_amdgcn_readfirstlane(offs[d]);
  int e1 = __builtin_amdgcn_readfirstlane(offs[d+1]);
  float a0=0.f, a1=0.f, a2=0.f, a3=0.f;
  for (int e = e0; e < e1; e += 8){
    int idx[8]; float msk[8];
    #pragma unroll
    for (int k=0;k<8;k++){
      int t = e + k;
      idx[k] = (t < e1) ? t : e0;
      msk[k] = (t < e1) ? 1.f : 0.f;
    }
    int s[8]; float4 c[8];
    #pragma unroll
    for (int k=0;k<8;k++){
      uint2 m = meta[idx[k]];
      unsigned pk = __builtin_amdgcn_readfirstlane(m.x);
      float nv = __uint_as_float(__builtin_amdgcn_readfirstlane(m.y));
      s[k] = (int)(pk & 0xFFFFFu);
      float4 cp = comp4[pk >> 20];
      c[k].x = cp.x*nv; c[k].y = cp.y*nv; c[k].z = cp.z*nv; c[k].w = cp.w*nv;
    }
    float x[8];
    #pragma unroll
    for (int k=0;k<8;k++)
      x[k] = emb[(size_t)s[k]*64 + lane] * msk[k];
    #pragma unroll
    for (int k=0;k<8;k++){
      a0 = fmaf(c[k].x, x[k], a0);
      a1 = fmaf(c[k].y, x[k], a1);
      a2 = fmaf(c[k].z, x[k], a2);
      a3 = fmaf(c[k].w, x[k], a3);
    }
  }
  ushort4 o; o.x=f2bf(a0); o.y=f2bf(a1); o.z=f2bf(a2); o.w=f2bf(a3);
  *(ushort4*)&zt[w][lane*4] = o;
  __syncthreads();
  if (w < 4){
    int quad = lane>>4, l15 = lane&15;
    bf16x8 a[8];
    #pragma unroll
    for (int kk=0; kk<8; kk++)
      a[kk] = *(const bf16x8*)&zt[l15][kk*32 + quad*8];
    floatx4 acc = {0.f,0.f,0.f,0.f};
    #pragma unroll
    for (int kk=0; kk<8; kk++){
      bf16x8 b = *((const bf16x8*)(Btab + ((w*8 + kk)*64 + lane)*8));
      acc = __builtin_amdgcn_mfma_f32_16x16x32_bf16(a[kk], b, acc, 0, 0, 0);
    }
    int col = w*16 + l15;
    float bv = bias[col];
    #pragma unroll
    for (int r=0; r<4; r++){
      int row = mbase + quad*4 + r;
      float v = fmaxf(acc[r] + bv, 0.f);
      h_bf[(size_t)row*64 + col] = f2bf(v);
    }
  }
}

__global__ __launch_bounds__(1024) void k_agg_gemm2(
    const ushort* __restrict__ hin, const int* __restrict__ offs,
    const uint2* __restrict__ meta, const float4* __restrict__ comp4,
    const ushort* __restrict__ Btab, const float* __restrict__ bias,
    float* __restrict__ out){
  __shared__ ushort zt[16][264];
  int lane = threadIdx.x & 63;
  int w = threadIdx.x >> 6;            // 0..15, one dst row per wave
  int mbase = blockIdx.x * 16;
  int d = mbase + w;
  int e0 = __builtin_amdgcn_readfirstlane(offs[d]);
  int e1 = __builtin_amdgcn_readfirstlane(offs[d+1]);
  float a0=0.f, a1=0.f, a2=0.f, a3=0.f;
  for (int e = e0; e < e1; e += 8){
    int idx[8]; float msk[8];
    #pragma unroll
    for (int k=0;k<8;k++){
      int t = e + k;
      idx[k] = (t < e1) ? t : e0;
      msk[k] = (t < e1) ? 1.f : 0.f;
    }
    int s[8]; float4 c[8];
    #pragma unroll
    for (int k=0;k<8;k++){
      uint2 m = meta[idx[k]];
      unsigned pk = __builtin_amdgcn_readfirstlane(m.x);
      float nv = __uint_as_float(__builtin_amdgcn_readfirstlane(m.y));
      s[k] = (int)(pk & 0xFFFFFu);
      float4 cp = comp4[pk >> 20];
      c[k].x = cp.x*nv; c[k].y = cp.y*nv; c[k].z = cp.z*nv; c[k].w = cp.w*nv;
    }
    float x[8];
    #pragma unroll
    for (int k=0;k<8;k++)
      x[k] = bf2f(hin[(size_t)s[k]*64 + lane]) * msk[k];
    #pragma unroll
    for (int k=0;k<8;k++){
      a0 = fmaf(c[k].x, x[k], a0);
      a1 = fmaf(c[k].y, x[k], a1);
      a2 = fmaf(c[k].z, x[k], a2);
      a3 = fmaf(c[k].w, x[k], a3);
    }
  }
  ushort4 o; o.x=f2bf(a0); o.y=f2bf(a1); o.z=f2bf(a2); o.w=f2bf(a3);
  *(ushort4*)&zt[w][lane*4] = o;
  __syncthreads();
  if (w < 2){                           // N=32 -> 2 n-tiles
    int quad = lane>>4, l15 = lane&15;
    bf16x8 a[8];
    #pragma unroll
    for (int kk=0; kk<8; kk++)
      a[kk] = *(const bf16x8*)&zt[l15][kk*32 + quad*8];
    floatx4 acc = {0.f,0.f,0.f,0.f};
    #pragma unroll
    for (int kk=0; kk<8; kk++){
      bf16x8 b = *((const bf16x8*)(Btab + ((w*8 + kk)*64 + lane)*8));
      acc = __builtin_amdgcn_mfma_f32_16x16x32_bf16(a[kk], b, acc, 0, 0, 0);
    }
    int col = w*16 + l15;
    float bv = bias[col];
    #pragma unroll
    for (int r=0; r<4; r++){
      int row = mbase + quad*4 + r;
      out[(size_t)row*32 + col] = acc[r] + bv;
    }
  }
}

extern "C" void kernel_launch(void* const* d_in, const int* in_sizes, int n_in,
                              void* d_out, int out_size, void* d_ws, size_t ws_size,
                              hipStream_t stream){
  const int*   input_nodes = (const int*)  d_in[0];
  const int*   src1  = (const int*)  d_in[1];
  const int*   dst1  = (const int*)  d_in[2];
  const int*   ety1  = (const int*)  d_in[3];
  const float* norm1 = (const float*)d_in[4];
  const int*   src2  = (const int*)  d_in[5];
  const int*   dst2  = (const int*)  d_in[6];
  const int*   ety2  = (const int*)  d_in[7];
  const float* norm2 = (const float*)d_in[8];
  const float* emb   = (const float*)d_in[9];
  const float* V1    = (const float*)d_in[10];
  const float* comp1 = (const float*)d_in[11];
  const float* b1    = (const float*)d_in[12];
  const float* V2    = (const float*)d_in[13];
  const float* comp2 = (const float*)d_in[14];
  const float* b2    = (const float*)d_in[15];
  float* out = (float*)d_out;

  char* p = (char*)d_ws;
  auto alloc = [&](size_t bytes)->char*{
    char* r = p; p += (bytes + 255) & ~(size_t)255; return r;
  };
  ushort* h_bf  = (ushort*)alloc((size_t)N_DST1*64*2);     // 12.8 MB
  ushort* Btab1 = (ushort*)alloc(16384*2);
  ushort* Btab2 = (ushort*)alloc(8192*2);
  int* deg  = (int*)alloc((size_t)NDST_TOT*4);
  int* cur  = (int*)alloc((size_t)NDST_TOT*4);
  int* offs = (int*)alloc((size_t)(NDST_TOT+1)*4);
  int* bs   = (int*)alloc(256*4);
  int* bo   = (int*)alloc(256*4);
  uint2* meta = (uint2*)alloc((size_t)E_TOT*8);

  // 1. init (deg zero + B tables)
  k_init<<<(NDST_TOT + 255)/256, 256, 0, stream>>>(V1, V2, Btab1, Btab2, deg);
  // 2. histogram (both graphs batched)
  k_hist<<<(E_TOT + 255)/256, 256, 0, stream>>>(dst1, dst2, deg);
  // 3-5. parallel 3-kernel exclusive scan
  int nb = (NDST_TOT + 1023)/1024;   // 118
  k_scan_sum<<<nb, 256, 0, stream>>>(deg, bs, NDST_TOT);
  k_scan_bsum<<<1, 256, 0, stream>>>(bs, bo, nb);
  k_scan_final<<<nb, 256, 0, stream>>>(deg, bo, offs, cur, NDST_TOT);
  // 6. scatter both graphs (packed 8 B meta; resolves input_nodes for L1)
  k_scatter<<<(E_TOT + 255)/256, 256, 0, stream>>>(input_nodes,
                                                   src1, dst1, ety1, norm1,
                                                   src2, dst2, ety2, norm2,
                                                   cur, meta);
  // 7. layer 1 fused agg(direct emb)+gemm (+relu)
  k_agg_gemm1<<<N_DST1/16, 1024, 0, stream>>>(emb, offs, meta,
                                              (const float4*)comp1, Btab1, b1, h_bf);
  // 8. layer 2 fused agg+gemm -> out
  k_agg_gemm2<<<N_DST2/16, 1024, 0, stream>>>(h_bf, offs + N_DST1, meta,
                                              (const float4*)comp2, Btab2, b2, out);

  (void)in_sizes; (void)n_in; (void)out_size; (void)ws_size;
}